// Round 1
// baseline (1130.702 us; speedup 1.0000x reference)
//
#include <hip/hip_runtime.h>
#include <math.h>

#define B_ 2048
#define D_ 512
#define N_ 64
#define M_ 32

// ---------- helpers ----------
__device__ __forceinline__ float wave_sum64(float v) {
#pragma unroll
  for (int o = 32; o > 0; o >>= 1) v += __shfl_xor(v, o, 64);
  return v;
}

// max with first-occurrence (lowest index) tie-break, butterfly -> all lanes
__device__ __forceinline__ void wave_argmax64(float& v, int& i) {
#pragma unroll
  for (int o = 32; o > 0; o >>= 1) {
    float ov = __shfl_xor(v, o, 64);
    int oi = __shfl_xor(i, o, 64);
    if (ov > v || (ov == v && oi < i)) { v = ov; i = oi; }
  }
}

__device__ __forceinline__ float sigmoidf_(float x) { return 1.0f / (1.0f + expf(-x)); }

__device__ __forceinline__ float d8(const float4& a0, const float4& a1,
                                    const float4& b0, const float4& b1) {
  return a0.x * b0.x + a0.y * b0.y + a0.z * b0.z + a0.w * b0.w +
         a1.x * b1.x + a1.y * b1.y + a1.z * b1.z + a1.w * b1.w;
}

// ---------- kernel 1: episodic priority + gate scalars ----------
__global__ __launch_bounds__(256) void k_episodic_gates(
    const float* __restrict__ ep_values, const float* __restrict__ ep_str,
    const float* __restrict__ ep_replay, const float* __restrict__ ep_age,
    const float* __restrict__ signal, const float* __restrict__ hidden,
    const float* __restrict__ branch_hint, const float* __restrict__ aentropy,
    const float* __restrict__ delay_gate,
    const float* __restrict__ fg_W, const float* __restrict__ fg_b,
    const float* __restrict__ pg_W, const float* __restrict__ pg_b,
    const float* __restrict__ cg_W, const float* __restrict__ cg_b,
    float* __restrict__ cons, float* __restrict__ persv, float* __restrict__ kfv,
    float* __restrict__ compv, int* __restrict__ srcix) {
  int b = blockIdx.x;
  int tid = threadIdx.x;
  int lane = tid & 63, w = tid >> 6;
  __shared__ float ssq[M_];
  __shared__ float prio[M_];
  __shared__ float red[4][3];

  // episodic value squared norms: wave w handles rows [w*8, w*8+8)
  // coalesced: float4 index {lane, lane+64} covers the 512-float row with
  // two fully-contiguous 1 KiB wave transactions
  for (int m = w * 8; m < w * 8 + 8; ++m) {
    const float4* row = (const float4*)(ep_values + ((size_t)(b * M_ + m)) * D_);
    float4 x0 = row[lane], x1 = row[lane + 64];
    float s = d8(x0, x1, x0, x1);
    s = wave_sum64(s);
    if (lane == 0) ssq[m] = s;
  }

  // gate dot products over routed[0:1024] (signal ++ hidden)
  float f = 0.f, p = 0.f, c = 0.f;
  for (int i = tid; i < 2 * D_; i += 256) {
    float r = (i < D_) ? signal[(size_t)b * D_ + i] : hidden[(size_t)b * D_ + i - D_];
    f += r * fg_W[i];
    p += r * pg_W[i];
    c += r * cg_W[i];
  }
  f = wave_sum64(f); p = wave_sum64(p); c = wave_sum64(c);
  if (lane == 0) { red[w][0] = f; red[w][1] = p; red[w][2] = c; }
  __syncthreads();

  if (tid < M_) {
    int m = tid;
    float nrm = sqrtf(ssq[m]) * 0.04419417382f;  // 1/sqrt(512)
    prio[m] = 0.45f * ep_str[(size_t)b * M_ + m] +
              0.3f * (ep_replay[(size_t)b * M_ + m] * (1.0f / 6.0f)) +
              0.15f * (1.0f - ep_age[(size_t)b * M_ + m]) +
              0.1f * fminf(fmaxf(nrm, 0.0f), 1.0f);
  }
  __syncthreads();

  if (tid == 0) {
    float fd = red[0][0] + red[1][0] + red[2][0] + red[3][0];
    float pd = red[0][1] + red[1][1] + red[2][1] + red[3][1];
    float cd = red[0][2] + red[1][2] + red[2][2] + red[3][2];
    for (int i = 0; i < 3; ++i) {
      float r = branch_hint[(size_t)b * 3 + i];
      fd += r * fg_W[2 * D_ + i];
      pd += r * pg_W[2 * D_ + i];
      cd += r * cg_W[2 * D_ + i];
    }
    float best = -1e30f; int bi = 0;
    for (int m = 0; m < M_; ++m)
      if (prio[m] > best) { best = prio[m]; bi = m; }
    float source_conf = best;
    float focus_base = sigmoidf_(fd + fg_b[0]);
    float compactness = sigmoidf_((0.72f - aentropy[b]) * 5.5f);
    float consolidation = sigmoidf_(cd + cg_b[0] + 2.2f * (source_conf - 0.5f));
    float persistence = sigmoidf_(pd + pg_b[0]);
    float key_focus = fminf(fmaxf(0.45f * focus_base + 0.3f * compactness + 0.25f * delay_gate[b], 0.0f), 1.0f);
    cons[b] = consolidation;
    persv[b] = persistence;
    kfv[b] = key_focus;
    compv[b] = compactness;
    srcix[b] = bi;
  }
}

// ---------- kernel 2: fused dual GEMM + tanh + episodic mix epilogue ----------
// C[b, col] = sum_k joined[b,k] * W[col,k];  cols [0,512)=key_W, [512,1024)=val_W
// LDS stride padded 64->68 (stride % 32 banks == 4): the scalar tile stores
// (4 lanes sharing lrow) drop from a 4-way bank conflict to a free 2-way.
__global__ __launch_bounds__(256) void k_gemm_mix(
    const float* __restrict__ signal, const float* __restrict__ hidden,
    const float* __restrict__ key_W, const float* __restrict__ key_b,
    const float* __restrict__ val_W, const float* __restrict__ val_b,
    const float* __restrict__ ep_keys, const float* __restrict__ ep_values,
    const float* __restrict__ cons, const int* __restrict__ srcix,
    float* __restrict__ mixed_key, float* __restrict__ mixed_value) {
  __shared__ __align__(16) float As[16][68];
  __shared__ __align__(16) float Bs[16][68];
  int tid = threadIdx.x;
  int tx = tid & 15, ty = tid >> 4;
  int bm = blockIdx.y * 64, bn = blockIdx.x * 64;
  int lrow = tid >> 2, lk4 = (tid & 3) * 4;
  float acc[4][4] = {};

  for (int kt = 0; kt < 2 * D_; kt += 16) {
    int k = kt + lk4;
    const float* asrc = (k < D_) ? (signal + (size_t)(bm + lrow) * D_ + k)
                                 : (hidden + (size_t)(bm + lrow) * D_ + (k - D_));
    float4 av = *(const float4*)asrc;
    int col = bn + lrow;
    const float* bsrc = (col < D_) ? (key_W + (size_t)col * (2 * D_) + k)
                                   : (val_W + (size_t)(col - D_) * (2 * D_) + k);
    float4 bv = *(const float4*)bsrc;
    As[lk4 + 0][lrow] = av.x; As[lk4 + 1][lrow] = av.y;
    As[lk4 + 2][lrow] = av.z; As[lk4 + 3][lrow] = av.w;
    Bs[lk4 + 0][lrow] = bv.x; Bs[lk4 + 1][lrow] = bv.y;
    Bs[lk4 + 2][lrow] = bv.z; Bs[lk4 + 3][lrow] = bv.w;
    __syncthreads();
#pragma unroll
    for (int kk = 0; kk < 16; ++kk) {
      float4 a = *(const float4*)&As[kk][ty * 4];
      float4 bb = *(const float4*)&Bs[kk][tx * 4];
      float ar[4] = {a.x, a.y, a.z, a.w};
      float br[4] = {bb.x, bb.y, bb.z, bb.w};
#pragma unroll
      for (int i2 = 0; i2 < 4; ++i2)
#pragma unroll
        for (int j2 = 0; j2 < 4; ++j2)
          acc[i2][j2] = fmaf(ar[i2], br[j2], acc[i2][j2]);
    }
    __syncthreads();
  }

#pragma unroll
  for (int i2 = 0; i2 < 4; ++i2) {
    int r = bm + ty * 4 + i2;
    float cv = cons[r];
    int s = srcix[r];
#pragma unroll
    for (int j2 = 0; j2 < 4; ++j2) {
      int col = bn + tx * 4 + j2;
      float x = acc[i2][j2];
      if (col < D_) {
        float t = tanhf(x + key_b[col]);
        float g = ep_keys[((size_t)r * M_ + s) * D_ + col];
        mixed_key[(size_t)r * D_ + col] = (1.0f - cv) * t + cv * g;
      } else {
        int c2 = col - D_;
        float t = tanhf(x + val_b[c2]);
        float g = ep_values[((size_t)r * M_ + s) * D_ + c2];
        mixed_value[(size_t)r * D_ + c2] = (1.0f - 0.35f * cv) * t + 0.35f * cv * g;
      }
    }
  }
}

// ---------- kernel 3: main pass over short-term memory ----------
// All row accesses use float4 index {lane, lane+64}: each instruction issues a
// fully-contiguous 1 KiB wave transaction (was 32 B-stride half-density pairs).
__global__ __launch_bounds__(256) void k_main(
    const float* __restrict__ query_key, const float* __restrict__ delay_gate,
    const float* __restrict__ salience_gate, const float* __restrict__ short_keys,
    const float* __restrict__ short_values, const float* __restrict__ short_strength,
    const float* __restrict__ short_age, const float* __restrict__ short_usage,
    const float* __restrict__ mixed_key, const float* __restrict__ mixed_value,
    const float* __restrict__ persv, const float* __restrict__ kfv,
    const float* __restrict__ compv,
    float* __restrict__ read_out, float* __restrict__ slot_hits,
    float* __restrict__ upd_keys, float* __restrict__ upd_values,
    float* __restrict__ upd_strength, float* __restrict__ upd_age,
    float* __restrict__ upd_usage) {
  int b = blockIdx.x;
  int tid = threadIdx.x;
  int lane = tid & 63, w = tid >> 6;
  __shared__ float keyscore[N_], simv[N_];
  __shared__ float scf[8];
  __shared__ int sci[4];

  // per-wave register-resident query slice and normalized candidate key slice
  const float4* qrow = (const float4*)(query_key + (size_t)b * D_);
  float4 qa = qrow[lane], qb = qrow[lane + 64];
  const float4* mkrow = (const float4*)(mixed_key + (size_t)b * D_);
  float4 ca = mkrow[lane], cb = mkrow[lane + 64];
  float ssqc = wave_sum64(d8(ca, cb, ca, cb));
  float cinv = 1.0f / fmaxf(sqrtf(ssqc), 1e-6f);
  ca.x *= cinv; ca.y *= cinv; ca.z *= cinv; ca.w *= cinv;
  cb.x *= cinv; cb.y *= cinv; cb.z *= cinv; cb.w *= cinv;

  // pass A: dots against each short_keys row + copy rows to output
  for (int n = w; n < N_; n += 4) {
    const float4* kr = (const float4*)(short_keys + ((size_t)b * N_ + n) * D_);
    float4 k0 = kr[lane], k1 = kr[lane + 64];
    float4* dst = (float4*)(upd_keys + ((size_t)b * N_ + n) * D_);
    dst[lane] = k0; dst[lane + 64] = k1;
    float ss = wave_sum64(d8(k0, k1, k0, k1));
    float qd = wave_sum64(d8(k0, k1, qa, qb));
    float cd = wave_sum64(d8(k0, k1, ca, cb));
    if (lane == 0) {
      float inv = 1.0f / fmaxf(sqrtf(ss), 1e-6f);
      keyscore[n] = qd * inv;
      simv[n] = cd * inv;
    }
  }
  __syncthreads();

  float s_n = 0.f, a_n = 0.f, u_n = 0.f;
  if (w == 0) {
    int n = lane;
    s_n = short_strength[(size_t)b * N_ + n];
    a_n = short_age[(size_t)b * N_ + n];
    u_n = short_usage[(size_t)b * N_ + n];
    float dg = delay_gate[b], sg = salience_gate[b];
    float pers_r = 2.8f * s_n + 0.9f * u_n + 0.6f * (1.0f - a_n);
    float score = 0.65f * keyscore[n] + 0.22f * pers_r + 0.08f * dg * a_n + 0.05f * sg * s_n;
    float repl = 1.3f * a_n + (1.0f - s_n) + 0.9f * (1.0f - u_n);

    float v0 = score; int i0 = n;
    wave_argmax64(v0, i0);
    float v1 = (n == i0) ? -1e30f : score; int i1 = n;
    wave_argmax64(v1, i1);
    float msim = simv[n]; int im = n;
    wave_argmax64(msim, im);
    float mr = repl; int ir = n;
    wave_argmax64(mr, ir);

    if (lane == 0) {
      float e = expf(2.0f * (v1 - v0));  // TEMP = 0.5
      float w1v = e / (1.0f + e);
      float w0v = 1.0f / (1.0f + e);
      bool um = msim > 0.81f;
      int t = um ? im : ir;
      float kf = kfv[b], cp = compv[b], pv = persv[b];
      float ow = (0.1f + 0.8f * kf) * (0.55f + 0.45f * cp);
      float km = um ? (0.18f + 0.24f * pv) : (0.78f + 0.1f * pv);
      float vm = um ? (0.34f + 0.22f * pv) : (0.82f + 0.1f * pv);
      float boost = ow * (0.55f + 0.2f * kf + 0.15f * pv);
      sci[0] = t; sci[1] = i0; sci[2] = i1;
      scf[0] = w0v; scf[1] = w1v; scf[2] = ow; scf[3] = km;
      scf[4] = vm; scf[5] = boost; scf[6] = dg;
    }
  }
  __syncthreads();

  int t = sci[0], i0 = sci[1], i1 = sci[2];
  float w0v = scf[0], w1v = scf[1], ow = scf[2], km = scf[3];
  float vm = scf[4], boost = scf[5], dgs = scf[6];

  // pass B: copy short_values rows, fixing up the target row inline
  for (int n = w; n < N_; n += 4) {
    const float4* vr = (const float4*)(short_values + ((size_t)b * N_ + n) * D_);
    float4 v0 = vr[lane], v1 = vr[lane + 64];
    if (n == t) {
      const float4* mv = (const float4*)(mixed_value + (size_t)b * D_);
      float4 m0 = mv[lane], m1 = mv[lane + 64];
      float fmix = ow * vm;
      v0.x += fmix * (tanhf(m0.x) - v0.x);
      v0.y += fmix * (tanhf(m0.y) - v0.y);
      v0.z += fmix * (tanhf(m0.z) - v0.z);
      v0.w += fmix * (tanhf(m0.w) - v0.w);
      v1.x += fmix * (tanhf(m1.x) - v1.x);
      v1.y += fmix * (tanhf(m1.y) - v1.y);
      v1.z += fmix * (tanhf(m1.z) - v1.z);
      v1.w += fmix * (tanhf(m1.w) - v1.w);
    }
    float4* dst = (float4*)(upd_values + ((size_t)b * N_ + n) * D_);
    dst[lane] = v0; dst[lane + 64] = v1;
  }

  // key target-row fixup (wave 0; ordering vs pass-A copy guaranteed by the
  // __syncthreads above, which drains vmem before the barrier)
  if (w == 0) {
    const float4* kr = (const float4*)(short_keys + ((size_t)b * N_ + t) * D_);
    float4 k0 = kr[lane], k1 = kr[lane + 64];
    float fmix = ow * km;
    k0.x += fmix * (ca.x - k0.x);
    k0.y += fmix * (ca.y - k0.y);
    k0.z += fmix * (ca.z - k0.z);
    k0.w += fmix * (ca.w - k0.w);
    k1.x += fmix * (cb.x - k1.x);
    k1.y += fmix * (cb.y - k1.y);
    k1.z += fmix * (cb.z - k1.z);
    k1.w += fmix * (cb.w - k1.w);
    float4* dst = (float4*)(upd_keys + ((size_t)b * N_ + t) * D_);
    dst[lane] = k0; dst[lane + 64] = k1;
  }

  // read_out: 256 threads x 2 elements (rows i0/i1 are L2-hot from pass B)
  {
    int e = tid * 2;
    float2 va = *(const float2*)(short_values + ((size_t)b * N_ + i0) * D_ + e);
    float2 vb = *(const float2*)(short_values + ((size_t)b * N_ + i1) * D_ + e);
    float2 ro;
    ro.x = w0v * va.x + w1v * vb.x;
    ro.y = w0v * va.y + w1v * vb.y;
    *(float2*)(read_out + (size_t)b * D_ + e) = ro;
  }

  // small per-slot outputs (wave 0 holds s_n/a_n/u_n in registers)
  if (w == 0) {
    int n = lane;
    float on_t = (n == t) ? ow : 0.0f;
    upd_strength[(size_t)b * N_ + n] =
        fminf(fmaxf(s_n * 0.97f + ((n == t) ? boost : 0.0f), 0.0f), 1.0f);
    upd_usage[(size_t)b * N_ + n] =
        fminf(fmaxf(u_n * 0.96f + on_t * (0.6f + 0.4f * dgs), 0.0f), 1.0f);
    upd_age[(size_t)b * N_ + n] =
        fminf(fmaxf((a_n + 0.02f) * (1.0f - 0.85f * on_t), 0.0f), 1.0f);
    slot_hits[(size_t)b * N_ + n] = (n == i0) ? w0v : ((n == i1) ? w1v : 0.0f);
  }
}

// ---------- launch ----------
extern "C" void kernel_launch(void* const* d_in, const int* in_sizes, int n_in,
                              void* d_out, int out_size, void* d_ws, size_t ws_size,
                              hipStream_t stream) {
  (void)in_sizes; (void)n_in; (void)out_size; (void)ws_size;
  const float* query_key     = (const float*)d_in[0];
  const float* delay_gate    = (const float*)d_in[1];
  const float* salience_gate = (const float*)d_in[2];
  const float* short_keys    = (const float*)d_in[3];
  const float* short_values  = (const float*)d_in[4];
  const float* short_strength= (const float*)d_in[5];
  const float* short_age     = (const float*)d_in[6];
  const float* short_usage   = (const float*)d_in[7];
  const float* signal        = (const float*)d_in[8];
  const float* hidden        = (const float*)d_in[9];
  const float* branch_hint   = (const float*)d_in[10];
  const float* aentropy      = (const float*)d_in[11];
  const float* ep_keys       = (const float*)d_in[12];
  const float* ep_values     = (const float*)d_in[13];
  const float* ep_str        = (const float*)d_in[14];
  const float* ep_replay     = (const float*)d_in[15];
  const float* ep_age        = (const float*)d_in[16];
  const float* key_W         = (const float*)d_in[17];
  const float* key_b         = (const float*)d_in[18];
  const float* val_W         = (const float*)d_in[19];
  const float* val_b         = (const float*)d_in[20];
  const float* fg_W          = (const float*)d_in[21];
  const float* fg_b          = (const float*)d_in[22];
  const float* pg_W          = (const float*)d_in[23];
  const float* pg_b          = (const float*)d_in[24];
  const float* cg_W          = (const float*)d_in[25];
  const float* cg_b          = (const float*)d_in[26];

  float* out = (float*)d_out;
  float* read_out     = out;
  float* slot_hits    = read_out + (size_t)B_ * D_;
  float* upd_keys     = slot_hits + (size_t)B_ * N_;
  float* upd_values   = upd_keys + (size_t)B_ * N_ * D_;
  float* upd_strength = upd_values + (size_t)B_ * N_ * D_;
  float* upd_age      = upd_strength + (size_t)B_ * N_;
  float* upd_usage    = upd_age + (size_t)B_ * N_;

  float* cons   = (float*)d_ws;
  float* persv  = cons + B_;
  float* kfv    = persv + B_;
  float* compv  = kfv + B_;
  int*   srcix  = (int*)(compv + B_);
  float* mixed_key   = (float*)(srcix + B_);
  float* mixed_value = mixed_key + (size_t)B_ * D_;

  k_episodic_gates<<<B_, 256, 0, stream>>>(
      ep_values, ep_str, ep_replay, ep_age, signal, hidden, branch_hint,
      aentropy, delay_gate, fg_W, fg_b, pg_W, pg_b, cg_W, cg_b,
      cons, persv, kfv, compv, srcix);

  dim3 g2(2 * D_ / 64, B_ / 64);  // (16, 32)
  k_gemm_mix<<<g2, 256, 0, stream>>>(
      signal, hidden, key_W, key_b, val_W, val_b, ep_keys, ep_values,
      cons, srcix, mixed_key, mixed_value);

  k_main<<<B_, 256, 0, stream>>>(
      query_key, delay_gate, salience_gate, short_keys, short_values,
      short_strength, short_age, short_usage, mixed_key, mixed_value,
      persv, kfv, compv, read_out, slot_hits, upd_keys, upd_values,
      upd_strength, upd_age, upd_usage);
}